// Round 1
// baseline (753.510 us; speedup 1.0000x reference)
//
#include <hip/hip_runtime.h>

// NConv depth-completion net, fp32 end-to-end.
// B=8 fixed. Encoder/decoder buffers ping-pong in d_ws (~199 MiB).

#define EPSN 1e-20f

__device__ __forceinline__ float softplusf(float x) {
    // matches jax.nn.softplus = max(x,0) + log1p(exp(-|x|))
    return fmaxf(x, 0.f) + log1pf(expf(-fabsf(x)));
}

// ---------------------------------------------------------------------------
// 5x5 normalized conv, pad=2, CO=4. CI=1 (FIRST: c0 = S>0.01 on the fly) or 4.
// One thread per output pixel, all 4 out channels. 16x16 tile + halo 2 in LDS.
// ---------------------------------------------------------------------------
template<int CI, bool FIRST>
__global__ __launch_bounds__(256) void nconv5(
    const float* __restrict__ xin, const float* __restrict__ cin,
    const float* __restrict__ wraw, const float* __restrict__ braw,
    float* __restrict__ xout, float* __restrict__ cout,
    int Hh, int Ww)
{
    const int TS = 16, HALO = 2, LT = TS + 2 * HALO;   // 20
    __shared__ float s_c [CI][LT][LT + 1];
    __shared__ float s_xc[CI][LT][LT + 1];
    __shared__ float s_w[4 * CI * 25];
    __shared__ float s_sum[4];
    __shared__ float s_b[4];

    const int b   = blockIdx.z;
    const int oh0 = blockIdx.y * TS, ow0 = blockIdx.x * TS;
    const int tid = threadIdx.y * 16 + threadIdx.x;

    for (int i = tid; i < 4 * CI * 25; i += 256) s_w[i] = softplusf(wraw[i]);
    if (tid < 4) s_b[tid] = braw[tid];
    __syncthreads();
    if (tid < 4) {
        float s = 0.f;
        for (int i = 0; i < CI * 25; ++i) s += s_w[tid * CI * 25 + i];
        s_sum[tid] = s;
    }

    const size_t plane = (size_t)Hh * Ww;
    for (int i = tid; i < LT * LT; i += 256) {
        int ly = i / LT, lx = i % LT;
        int ih = oh0 - HALO + ly, iw = ow0 - HALO + lx;
        bool ok = (ih >= 0 && ih < Hh && iw >= 0 && iw < Ww);
        #pragma unroll
        for (int ci = 0; ci < CI; ++ci) {
            float x = 0.f, c = 0.f;
            if (ok) {
                size_t idx = ((size_t)(b * CI + ci)) * plane + (size_t)ih * Ww + iw;
                x = xin[idx];
                if (FIRST) c = (x > 0.01f) ? 1.f : 0.f;
                else       c = cin[idx];
            }
            s_c [ci][ly][lx] = c;
            s_xc[ci][ly][lx] = x * c;
        }
    }
    __syncthreads();

    const int oh = oh0 + threadIdx.y, ow = ow0 + threadIdx.x;
    if (oh >= Hh || ow >= Ww) return;

    float nom[4] = {0.f, 0.f, 0.f, 0.f}, den[4] = {0.f, 0.f, 0.f, 0.f};
    #pragma unroll
    for (int kj = 0; kj < 5; ++kj)
    #pragma unroll
    for (int ki = 0; ki < 5; ++ki)
    #pragma unroll
    for (int ci = 0; ci < CI; ++ci) {
        float c  = s_c [ci][threadIdx.y + kj][threadIdx.x + ki];
        float xc = s_xc[ci][threadIdx.y + kj][threadIdx.x + ki];
        #pragma unroll
        for (int co = 0; co < 4; ++co) {
            float w = s_w[((co * CI + ci) * 5 + kj) * 5 + ki];
            nom[co] += w * xc;
            den[co] += w * c;
        }
    }
    size_t ob = ((size_t)(b * 4)) * plane + (size_t)oh * Ww + ow;
    #pragma unroll
    for (int co = 0; co < 4; ++co) {
        xout[ob + co * plane] = nom[co] / (den[co] + EPSN) + s_b[co];
        cout[ob + co * plane] = den[co] / s_sum[co];
    }
}

// ---------------------------------------------------------------------------
// 2x2 pool: argmax of confidence (first-max tie rule, order (0,0),(0,1),(1,0),(1,1)),
// gather x at argmax, c_out = max/4.
// ---------------------------------------------------------------------------
__global__ __launch_bounds__(256) void pool2k(
    const float* __restrict__ x, const float* __restrict__ c,
    float* __restrict__ xo, float* __restrict__ co, int Hh, int Ww)
{
    int H2 = Hh / 2, W2 = Ww / 2;
    int total = 8 * 4 * H2 * W2;
    int i = blockIdx.x * 256 + threadIdx.x;
    if (i >= total) return;
    int ow = i % W2;
    int oh = (i / W2) % H2;
    int ch = (i / (W2 * H2)) % 4;
    int b  =  i / (W2 * H2 * 4);
    size_t base = (((size_t)(b * 4 + ch)) * Hh + 2 * oh) * Ww + 2 * ow;
    float c00 = c[base], c01 = c[base + 1], c10 = c[base + Ww], c11 = c[base + Ww + 1];
    int k = 0; float cm = c00;
    if (c01 > cm) { cm = c01; k = 1; }
    if (c10 > cm) { cm = c10; k = 2; }
    if (c11 > cm) { cm = c11; k = 3; }
    float xv = (k == 0) ? x[base] : (k == 1) ? x[base + 1] : (k == 2) ? x[base + Ww] : x[base + Ww + 1];
    size_t ob = (((size_t)(b * 4 + ch)) * H2 + oh) * W2 + ow;
    xo[ob] = xv;
    co[ob] = cm * 0.25f;
}

// ---------------------------------------------------------------------------
// 3x3 normalized conv over concat of a direct 4ch source (H,W) and a
// nearest-2x-upsampled 4ch source (H/2,W/2). UP_FIRST: upsampled occupies
// channels 0-3 (w6) else 4-7 (w4,w5). PAD in {0,1}.
// ---------------------------------------------------------------------------
template<bool UP_FIRST, int PAD>
__global__ __launch_bounds__(256) void nconv3cat(
    const float* __restrict__ xd, const float* __restrict__ cd,
    const float* __restrict__ xu, const float* __restrict__ cu,
    const float* __restrict__ wraw, const float* __restrict__ braw,
    float* __restrict__ xout, float* __restrict__ cout,
    int Hin, int Win)
{
    const int TS = 16, LT = TS + 2;   // 18
    __shared__ float s_c [8][LT][LT + 1];
    __shared__ float s_xc[8][LT][LT + 1];
    __shared__ float s_w[288];
    __shared__ float s_sum[4];
    __shared__ float s_b[4];

    const int Hout = Hin - 2 + 2 * PAD, Wout = Win - 2 + 2 * PAD;
    const int b   = blockIdx.z;
    const int oh0 = blockIdx.y * TS, ow0 = blockIdx.x * TS;
    const int tid = threadIdx.y * 16 + threadIdx.x;

    for (int i = tid; i < 288; i += 256) s_w[i] = softplusf(wraw[i]);
    if (tid < 4) s_b[tid] = braw[tid];
    __syncthreads();
    if (tid < 4) {
        float s = 0.f;
        for (int i = 0; i < 72; ++i) s += s_w[tid * 72 + i];
        s_sum[tid] = s;
    }

    const int Hu = Hin / 2, Wu = Win / 2;
    const size_t planeD = (size_t)Hin * Win, planeU = (size_t)Hu * Wu;
    for (int i = tid; i < LT * LT; i += 256) {
        int ly = i / LT, lx = i % LT;
        int ih = oh0 - PAD + ly, iw = ow0 - PAD + lx;
        bool ok = (ih >= 0 && ih < Hin && iw >= 0 && iw < Win);
        #pragma unroll
        for (int ci = 0; ci < 4; ++ci) {
            float x = 0.f, c = 0.f;
            if (ok) {
                size_t idx = ((size_t)(b * 4 + ci)) * planeD + (size_t)ih * Win + iw;
                x = xd[idx]; c = cd[idx];
            }
            int ch = UP_FIRST ? ci + 4 : ci;
            s_c [ch][ly][lx] = c;
            s_xc[ch][ly][lx] = x * c;
        }
        #pragma unroll
        for (int ci = 0; ci < 4; ++ci) {
            float x = 0.f, c = 0.f;
            if (ok) {
                size_t idx = ((size_t)(b * 4 + ci)) * planeU + (size_t)(ih >> 1) * Wu + (iw >> 1);
                x = xu[idx]; c = cu[idx];
            }
            int ch = UP_FIRST ? ci : ci + 4;
            s_c [ch][ly][lx] = c;
            s_xc[ch][ly][lx] = x * c;
        }
    }
    __syncthreads();

    const int oh = oh0 + threadIdx.y, ow = ow0 + threadIdx.x;
    if (oh >= Hout || ow >= Wout) return;

    float nom[4] = {0.f, 0.f, 0.f, 0.f}, den[4] = {0.f, 0.f, 0.f, 0.f};
    #pragma unroll
    for (int kj = 0; kj < 3; ++kj)
    #pragma unroll
    for (int ki = 0; ki < 3; ++ki)
    #pragma unroll
    for (int ci = 0; ci < 8; ++ci) {
        float c  = s_c [ci][threadIdx.y + kj][threadIdx.x + ki];
        float xc = s_xc[ci][threadIdx.y + kj][threadIdx.x + ki];
        #pragma unroll
        for (int co = 0; co < 4; ++co) {
            float w = s_w[((co * 8 + ci) * 3 + kj) * 3 + ki];
            nom[co] += w * xc;
            den[co] += w * c;
        }
    }
    size_t planeO = (size_t)Hout * Wout;
    size_t ob = ((size_t)(b * 4)) * planeO + (size_t)oh * Wout + ow;
    #pragma unroll
    for (int co = 0; co < 4; ++co) {
        xout[ob + co * planeO] = nom[co] / (den[co] + EPSN) + s_b[co];
        cout[ob + co * planeO] = den[co] / s_sum[co];
    }
}

// ---------------------------------------------------------------------------
// 3x3 normalized conv, 4->4, pad=1 (w65). In-dims == out-dims.
// ---------------------------------------------------------------------------
__global__ __launch_bounds__(256) void nconv3p(
    const float* __restrict__ xin, const float* __restrict__ cin,
    const float* __restrict__ wraw, const float* __restrict__ braw,
    float* __restrict__ xout, float* __restrict__ cout,
    int Hh, int Ww)
{
    const int TS = 16, LT = TS + 2;
    __shared__ float s_c [4][LT][LT + 1];
    __shared__ float s_xc[4][LT][LT + 1];
    __shared__ float s_w[144];
    __shared__ float s_sum[4];
    __shared__ float s_b[4];

    const int b   = blockIdx.z;
    const int oh0 = blockIdx.y * TS, ow0 = blockIdx.x * TS;
    const int tid = threadIdx.y * 16 + threadIdx.x;

    for (int i = tid; i < 144; i += 256) s_w[i] = softplusf(wraw[i]);
    if (tid < 4) s_b[tid] = braw[tid];
    __syncthreads();
    if (tid < 4) {
        float s = 0.f;
        for (int i = 0; i < 36; ++i) s += s_w[tid * 36 + i];
        s_sum[tid] = s;
    }

    const size_t plane = (size_t)Hh * Ww;
    for (int i = tid; i < LT * LT; i += 256) {
        int ly = i / LT, lx = i % LT;
        int ih = oh0 - 1 + ly, iw = ow0 - 1 + lx;
        bool ok = (ih >= 0 && ih < Hh && iw >= 0 && iw < Ww);
        #pragma unroll
        for (int ci = 0; ci < 4; ++ci) {
            float x = 0.f, c = 0.f;
            if (ok) {
                size_t idx = ((size_t)(b * 4 + ci)) * plane + (size_t)ih * Ww + iw;
                x = xin[idx]; c = cin[idx];
            }
            s_c [ci][ly][lx] = c;
            s_xc[ci][ly][lx] = x * c;
        }
    }
    __syncthreads();

    const int oh = oh0 + threadIdx.y, ow = ow0 + threadIdx.x;
    if (oh >= Hh || ow >= Ww) return;

    float nom[4] = {0.f, 0.f, 0.f, 0.f}, den[4] = {0.f, 0.f, 0.f, 0.f};
    #pragma unroll
    for (int kj = 0; kj < 3; ++kj)
    #pragma unroll
    for (int ki = 0; ki < 3; ++ki)
    #pragma unroll
    for (int ci = 0; ci < 4; ++ci) {
        float c  = s_c [ci][threadIdx.y + kj][threadIdx.x + ki];
        float xc = s_xc[ci][threadIdx.y + kj][threadIdx.x + ki];
        #pragma unroll
        for (int co = 0; co < 4; ++co) {
            float w = s_w[((co * 4 + ci) * 3 + kj) * 3 + ki];
            nom[co] += w * xc;
            den[co] += w * c;
        }
    }
    size_t ob = ((size_t)(b * 4)) * plane + (size_t)oh * Ww + ow;
    #pragma unroll
    for (int co = 0; co < 4; ++co) {
        xout[ob + co * plane] = nom[co] / (den[co] + EPSN) + s_b[co];
        cout[ob + co * plane] = den[co] / s_sum[co];
    }
}

// ---------------------------------------------------------------------------
// 1x1 normalized conv 4->1 (w7). Confidence output unused downstream.
// In/out: (8,1,478,638)
// ---------------------------------------------------------------------------
__global__ __launch_bounds__(256) void nconv1f(
    const float* __restrict__ x, const float* __restrict__ c,
    const float* __restrict__ wraw, const float* __restrict__ braw,
    float* __restrict__ out)
{
    const int plane = 478 * 638;
    int total = 8 * plane;
    int i = blockIdx.x * 256 + threadIdx.x;
    if (i >= total) return;
    int b = i / plane, r = i % plane;
    float w0 = softplusf(wraw[0]), w1 = softplusf(wraw[1]),
          w2 = softplusf(wraw[2]), w3 = softplusf(wraw[3]);
    size_t base = (size_t)b * 4 * plane + r;
    float nom = 0.f, den = 0.f;
    nom += w0 * x[base + 0 * (size_t)plane] * c[base + 0 * (size_t)plane];
    den += w0 * c[base + 0 * (size_t)plane];
    nom += w1 * x[base + 1 * (size_t)plane] * c[base + 1 * (size_t)plane];
    den += w1 * c[base + 1 * (size_t)plane];
    nom += w2 * x[base + 2 * (size_t)plane] * c[base + 2 * (size_t)plane];
    den += w2 * c[base + 2 * (size_t)plane];
    nom += w3 * x[base + 3 * (size_t)plane] * c[base + 3 * (size_t)plane];
    den += w3 * c[base + 3 * (size_t)plane];
    out[i] = nom / (den + EPSN) + braw[0];
}

// ---------------------------------------------------------------------------
// Adaptive average pool (478,638) -> (480,640), separable windows of 1-2.
// ---------------------------------------------------------------------------
__global__ __launch_bounds__(256) void apoolk(
    const float* __restrict__ in, float* __restrict__ out)
{
    const int HI = 478, WI = 638, HO = 480, WO = 640;
    int total = 8 * HO * WO;
    int i = blockIdx.x * 256 + threadIdx.x;
    if (i >= total) return;
    int ow = i % WO;
    int oh = (i / WO) % HO;
    int b  = i / (WO * HO);
    int sh = (oh * HI) / HO, eh = ((oh + 1) * HI + HO - 1) / HO;
    int sw = (ow * WI) / WO, ew = ((ow + 1) * WI + WO - 1) / WO;
    float s = 0.f;
    for (int ih = sh; ih < eh; ++ih)
        for (int iw = sw; iw < ew; ++iw)
            s += in[((size_t)b * HI + ih) * WI + iw];
    out[i] = s / (float)((eh - sh) * (ew - sw));
}

// ---------------------------------------------------------------------------
extern "C" void kernel_launch(void* const* d_in, const int* in_sizes, int n_in,
                              void* d_out, int out_size, void* d_ws, size_t ws_size,
                              hipStream_t stream)
{
    // setup_inputs order: fout, S, K, then (w,b) pairs for 1,2,3,4,5,6,65,7
    const float* S   = (const float*)d_in[1];
    const float* w1  = (const float*)d_in[3];  const float* b1  = (const float*)d_in[4];
    const float* w2  = (const float*)d_in[5];  const float* b2  = (const float*)d_in[6];
    const float* w3  = (const float*)d_in[7];  const float* b3  = (const float*)d_in[8];
    const float* w4  = (const float*)d_in[9];  const float* b4  = (const float*)d_in[10];
    const float* w5  = (const float*)d_in[11]; const float* b5  = (const float*)d_in[12];
    const float* w6  = (const float*)d_in[13]; const float* b6  = (const float*)d_in[14];
    const float* w65 = (const float*)d_in[15]; const float* b65 = (const float*)d_in[16];
    const float* w7  = (const float*)d_in[17]; const float* b7  = (const float*)d_in[18];
    float* out = (float*)d_out;
    float* ws  = (float*)d_ws;

    const size_t FULL = 9830400, HALF = 2457600, QUAR = 614400, EIGH = 153600;
    float *A0 = ws,        *A1 = A0 + FULL, *A2 = A1 + FULL, *A3 = A2 + FULL;
    float *P0 = A3 + FULL, *P1 = P0 + HALF, *P2 = P1 + HALF, *P3 = P2 + HALF;
    float *Q0 = P3 + HALF, *Q1 = Q0 + QUAR, *Q2 = Q1 + QUAR, *Q3 = Q2 + QUAR;
    float *E0 = Q3 + QUAR, *E1 = E0 + EIGH, *E2 = E1 + EIGH, *E3 = E2 + EIGH;

    dim3 blk(16, 16);
    auto grd = [](int H, int W) { return dim3((W + 15) / 16, (H + 15) / 16, 8); };

    // encoder, full res: S -> x1,c1 (kept in A0,A1)
    nconv5<1, true ><<<grd(480, 640), blk, 0, stream>>>(S,  S,  w1, b1, A0, A1, 480, 640);
    nconv5<4, false><<<grd(480, 640), blk, 0, stream>>>(A0, A1, w2, b2, A2, A3, 480, 640);
    nconv5<4, false><<<grd(480, 640), blk, 0, stream>>>(A2, A3, w3, b3, A0, A1, 480, 640);
    // 1/2 scale
    pool2k<<<(8 * 4 * 240 * 320 + 255) / 256, 256, 0, stream>>>(A0, A1, P0, P1, 480, 640);
    nconv5<4, false><<<grd(240, 320), blk, 0, stream>>>(P0, P1, w2, b2, P2, P3, 240, 320);
    nconv5<4, false><<<grd(240, 320), blk, 0, stream>>>(P2, P3, w3, b3, P0, P1, 240, 320); // x2_ds in P0,P1
    // 1/4 scale
    pool2k<<<(8 * 4 * 120 * 160 + 255) / 256, 256, 0, stream>>>(P0, P1, Q0, Q1, 240, 320);
    nconv5<4, false><<<grd(120, 160), blk, 0, stream>>>(Q0, Q1, w2, b2, Q2, Q3, 120, 160); // x3_ds in Q2,Q3
    // 1/8 scale
    pool2k<<<(8 * 4 * 60 * 80 + 255) / 256, 256, 0, stream>>>(Q2, Q3, E0, E1, 120, 160);
    nconv5<4, false><<<grd(60, 80), blk, 0, stream>>>(E0, E1, w2, b2, E2, E3, 60, 80);     // x4_ds in E2,E3
    // decoder
    nconv3cat<false, 1><<<grd(120, 160), blk, 0, stream>>>(Q2, Q3, E2, E3, w4, b4, Q0, Q1, 120, 160); // x34_ds
    nconv3cat<false, 1><<<grd(240, 320), blk, 0, stream>>>(P0, P1, Q0, Q1, w5, b5, P2, P3, 240, 320); // x23_ds
    nconv3cat<true , 0><<<grd(478, 638), blk, 0, stream>>>(A0, A1, P2, P3, w6, b6, A2, A3, 480, 640); // xo 478x638
    nconv3p<<<grd(478, 638), blk, 0, stream>>>(A2, A3, w65, b65, A0, A1, 478, 638);
    nconv1f<<<(8 * 478 * 638 + 255) / 256, 256, 0, stream>>>(A0, A1, w7, b7, A2);
    apoolk<<<(8 * 480 * 640 + 255) / 256, 256, 0, stream>>>(A2, out);
}